// Round 7
// baseline (4630.524 us; speedup 1.0000x reference)
//
#include <hip/hip_runtime.h>
#include <hip/hip_bf16.h>
#include <stdint.h>

typedef __attribute__((ext_vector_type(4))) float f32x4;
typedef __attribute__((ext_vector_type(8))) short bf16x8;

// ---- workspace layout (bytes) ----
#define WS_XBF   0u          // x gathered, bf16 [S=512][B=32][E=256]          = 8388608
#define WS_WIR   8388608u    // Wi permuted rows, bf16 [2048][256]             = 1048576
#define WS_BIAS  9437184u    // bi+bh permuted, f32 [2048]                     = 8192
#define WS_PRE   9445376u    // pre, bf16 [2][512 s][4 slice][512 tid][16]     = 67108864
#define WS_HALL  76554240u   // h halves: [2 dir][2 b2][513 st][2 uh][16 r][128 u] bf16 = 16809984
#define WS_CTL   93364224u   // XCD-team claim control block (16 u32, in gap)
#define WS_EMIS  93368320u   // emissions f32 [32 b][512 s][16 t]              = 1048576
#define WS_CHK   94416896u   // CRF chunk mats f32 [32 b][32 c][16][16]        = 1048576
// flags alias CHK (k_crfc runs after k_rec): u32 [(dir*2+b2)*513+st][2 uh][32 pad]
#define WS_FLG   WS_CHK      // 4*513*2*32*4 = 525312 B < 1 MiB

__device__ __forceinline__ unsigned short f2bf(float x) {
    union { float f; unsigned int u; } v; v.f = x;
    return (unsigned short)((v.u + 0x7FFFu + ((v.u >> 16) & 1u)) >> 16);
}
__device__ __forceinline__ float bf2f(unsigned short b) {
    union { float f; unsigned int u; } v; v.u = ((unsigned int)b) << 16; return v.f;
}
__device__ __forceinline__ unsigned int pack2(float a, float b) {
    return (unsigned int)f2bf(a) | ((unsigned int)f2bf(b) << 16);
}
__device__ __forceinline__ float sigf(float x)  { return 1.0f / (1.0f + __expf(-x)); }
__device__ __forceinline__ float tanhf_(float x){ return 1.0f - 2.0f / (__expf(2.0f * x) + 1.0f); }

// LDS-only barrier: waits lgkmcnt only; in-flight global ops keep flying.
__device__ __forceinline__ void lds_barrier() {
    asm volatile("s_waitcnt lgkmcnt(0)" ::: "memory");
    __builtin_amdgcn_s_barrier();
    __builtin_amdgcn_sched_barrier(0);
}

// ============ kernel 1: gather x -> bf16, permute Wi rows, combine biases, zero h/flags ============
__global__ __launch_bounds__(256) void k_prep(
    const int* __restrict__ tokens, const float* __restrict__ embed,
    const float* __restrict__ Wi_f, const float* __restrict__ Wi_b,
    const float* __restrict__ bi_f, const float* __restrict__ bh_f,
    const float* __restrict__ bi_b, const float* __restrict__ bh_b,
    char* __restrict__ ws)
{
    int blk = blockIdx.x, tid = threadIdx.x;
    unsigned short* xbf  = (unsigned short*)(ws + WS_XBF);
    unsigned short* wir  = (unsigned short*)(ws + WS_WIR);
    float* biasr         = (float*)(ws + WS_BIAS);
    if (blk < 2048) {                       // x gather: 8 rows/block
        int rr = tid >> 5, cc = tid & 31;
        int r = blk * 8 + rr;               // r = s*32+b
        int s = r >> 5, b = r & 31;
        int tok = tokens[b * 512 + s];
        int k = cc * 8;
        const float* src = embed + (size_t)tok * 256 + k;
        float4 a = *(const float4*)src;
        float4 c = *(const float4*)(src + 4);
        uint4 o; o.x = pack2(a.x, a.y); o.y = pack2(a.z, a.w);
        o.z = pack2(c.x, c.y); o.w = pack2(c.z, c.w);
        *(uint4*)(xbf + (size_t)r * 256 + k) = o;
    } else if (blk < 2304) {                // Wi row permute: dest row' = dir*1024 + j*256 + (g*64+hl)
        int rr = tid >> 5, cc = tid & 31;
        int rowp = (blk - 2048) * 8 + rr;   // 0..2047
        int dir = rowp >> 10, q = rowp & 1023;
        int j = q >> 8, rs = q & 255;
        int g = rs >> 6, hl = rs & 63;
        int srow = g * 256 + j * 64 + hl;
        const float* W = dir ? Wi_b : Wi_f;
        int k = cc * 8;
        const float* src = W + (size_t)srow * 256 + k;
        float4 a = *(const float4*)src;
        float4 c = *(const float4*)(src + 4);
        uint4 o; o.x = pack2(a.x, a.y); o.y = pack2(a.z, a.w);
        o.z = pack2(c.x, c.y); o.w = pack2(c.z, c.w);
        *(uint4*)(wir + (size_t)rowp * 256 + k) = o;
        if (cc == 0)
            biasr[rowp] = dir ? (bi_b[srow] + bh_b[srow]) : (bi_f[srow] + bh_f[srow]);
    } else {                                // zero h buffers (slot 0 = h0 = 0), ctl, flags
        if (blk == 2304 && tid < 16)
            ((unsigned int*)(ws + WS_CTL))[tid] = 0u;
        if (blk == 2305) {                  // zero the step-ready flag array
            unsigned int* flg = (unsigned int*)(ws + WS_FLG);
            for (int u = tid; u < 4 * 513 * 2 * 32; u += 256) flg[u] = 0u;
        }
        size_t g = (size_t)(blk - 2304) * 256 + tid;
        uint4* hall4 = (uint4*)(ws + WS_HALL);
        uint4 z; z.x = 0u; z.y = 0u; z.z = 0u; z.w = 0u;
        for (size_t u = g; u < 1050624u; u += 65536u)     // 16,809,984 B / 16
            hall4[u] = z;
    }
}

// ============ kernel 2: pre = x*Wi^T + bias, written in recurrence-lane-private layout ============
__global__ __launch_bounds__(256) void k_pregemm(char* __restrict__ ws)
{
    __shared__ unsigned short Asb[128 * 136];
    __shared__ unsigned short Bsb[64 * 136];
    const unsigned short* xbf = (const unsigned short*)(ws + WS_XBF);
    const unsigned short* wir = (const unsigned short*)(ws + WS_WIR);
    const float* biasr        = (const float*)(ws + WS_BIAS);
    unsigned short* pre       = (unsigned short*)(ws + WS_PRE);
    int blk = blockIdx.x, tid = threadIdx.x;
    int mb = blk >> 5, nb = blk & 31;
    int Mbase = mb * 128, Nbase = nb * 64;
    int w = tid >> 6, l = tid & 63, col = l & 15, quad = l >> 4;
    f32x4 acc[4][2];
    #pragma unroll
    for (int a = 0; a < 4; ++a)
        #pragma unroll
        for (int b = 0; b < 2; ++b) acc[a][b] = (f32x4){0.f, 0.f, 0.f, 0.f};

    for (int kh = 0; kh < 2; ++kh) {
        __syncthreads();
        #pragma unroll
        for (int i = 0; i < 8; ++i) {       // A half-tile 128x128 bf16
            int c = tid + i * 256;
            int row = c >> 4, c16 = c & 15;
            uint4 v = *(const uint4*)(xbf + ((size_t)(Mbase + row) * 256 + kh * 128 + c16 * 8));
            *(uint4*)(Asb + row * 136 + c16 * 8) = v;
        }
        #pragma unroll
        for (int i = 0; i < 4; ++i) {       // B half-tile 64x128 bf16
            int c = tid + i * 256;
            int row = c >> 4, c16 = c & 15;
            uint4 v = *(const uint4*)(wir + ((size_t)(Nbase + row) * 256 + kh * 128 + c16 * 8));
            *(uint4*)(Bsb + row * 136 + c16 * 8) = v;
        }
        __syncthreads();
        int mhalf = w >> 1, nh = w & 1;
        #pragma unroll
        for (int kt = 0; kt < 4; ++kt) {
            bf16x8 bfr[2];
            #pragma unroll
            for (int nn = 0; nn < 2; ++nn)
                bfr[nn] = *(const bf16x8*)(Bsb + (16 * (nh * 2 + nn) + col) * 136 + kt * 32 + quad * 8);
            #pragma unroll
            for (int mm = 0; mm < 4; ++mm) {
                bf16x8 afr = *(const bf16x8*)(Asb + (16 * (mhalf * 4 + mm) + col) * 136 + kt * 32 + quad * 8);
                #pragma unroll
                for (int nn = 0; nn < 2; ++nn)
                    acc[mm][nn] = __builtin_amdgcn_mfma_f32_16x16x32_bf16(afr, bfr[nn], acc[mm][nn], 0, 0, 0);
            }
        }
    }
    // epilogue: + bias, bf16, permuted store matching recurrence lane layout
    #pragma unroll
    for (int mm = 0; mm < 4; ++mm) {
        int m_t = (w >> 1) * 4 + mm;
        int s = (Mbase >> 5) + (m_t >> 1);
        int bhalf = m_t & 1;
        #pragma unroll
        for (int nn = 0; nn < 2; ++nn) {
            int ncol = Nbase + 16 * ((w & 1) * 2 + nn) + col;
            int dir = ncol >> 10, j = (ncol >> 8) & 3, r = ncol & 255;
            int g = r >> 6, hl16 = (r >> 4) & 3;
            int tidp = (bhalf * 4 + hl16) * 64 + l;
            float bv = biasr[ncol];
            f32x4 a = acc[mm][nn];
            uint2 o;
            o.x = pack2(a[0] + bv, a[1] + bv);
            o.y = pack2(a[2] + bv, a[3] + bv);
            size_t off = (((size_t)(dir * 512 + s) * 4 + j) * 512 + tidp) * 16 + g * 4;
            *(uint2*)(pre + off) = o;
        }
    }
}

// ============ kernel 3: persistent bidirectional LSTM recurrence ============
// Round-7: BATCH-INDEPENDENCE restructure. The LSTM couples units, never batch rows,
// so blocks split (dir x batch-half x unit-half): 8 blocks, each 16 batch rows x 128
// units, weights fully register-resident (128 VGPR/wave). Cross-block traffic drops
// from 4-way all-to-all 16KB/step to PAIRWISE 4KB/step with ONE partner, and the wait
// is overlapped: [own-half K MFMAs] run while the partner flag is polled. Protocol =
// r6-proven pieces only: 1 CAS poller + LDS fanout, plain one-shot cold-line data
// loads after RMW-detected flag, plain publish stores + vmcnt drain + barrier + one
// flag swap. Six rounds showed the 4-way exchange has a ~5-6k cy/step floor invariant
// to protocol; this attacks the structure instead.
__global__ __launch_bounds__(512, 2) void k_rec(
    const float* __restrict__ Wh_f, const float* __restrict__ Wh_b, char* __restrict__ ws)
{
    __shared__ unsigned short hbuf[2 * 16 * 264];   // [parity][16 rows][256 units +8 pad]
    __shared__ char stpad[71680];                   // occupancy limiter -> 1 block/CU
    __shared__ int sRole;
    __shared__ int go;
    int tid = threadIdx.x;

    // ---- XCD team claim (proven r1-r6) ----
    if (tid == 0) {
        ((volatile char*)stpad)[0] = 0;
        go = 0;
        int xcd;
        asm volatile("s_getreg_b32 %0, hwreg(HW_REG_XCC_ID)" : "=s"(xcd));
        xcd &= 7;
        unsigned int* ctl = (unsigned int*)(ws + WS_CTL);
        unsigned int slot = __hip_atomic_fetch_add(&ctl[xcd], 1u,
                              __ATOMIC_RELAXED, __HIP_MEMORY_SCOPE_AGENT);
        int role = -1;
        if (slot < 8u) {
            if (slot == 7u) {
                unsigned int expv = 0u;
                __hip_atomic_compare_exchange_strong(&ctl[8], &expv, (unsigned int)(xcd + 1),
                    __ATOMIC_RELAXED, __ATOMIC_RELAXED, __HIP_MEMORY_SCOPE_AGENT);
            }
            unsigned int ts; long gc = 0;
            do {
                ts = __hip_atomic_fetch_add(&ctl[8], 0u,
                        __ATOMIC_RELAXED, __HIP_MEMORY_SCOPE_AGENT);
            } while (ts == 0u && ++gc < (1L << 26));
            if (ts == (unsigned int)(xcd + 1)) role = (int)slot;
        }
        sRole = role;
    }
    __syncthreads();
    int role = sRole;
    if (role < 0) return;
    int dir = role >> 2, b2 = (role >> 1) & 1, uh = role & 1;

    int w = tid >> 6, l = tid & 63, col = l & 15, quad = l >> 4;
    const float* Wh = dir ? Wh_b : Wh_f;
    const unsigned short* pre = (const unsigned short*)(ws + WS_PRE);
    unsigned short* hall      = (unsigned short*)(ws + WS_HALL);
    unsigned int* flags       = (unsigned int*)(ws + WS_FLG);

    // persistent weight B-fragments: wf[gate][kt], Wh rows g*256 + uh*128 + w*16 + col
    bf16x8 wf[4][8];
    #pragma unroll
    for (int g = 0; g < 4; ++g) {
        int grow = g * 256 + uh * 128 + w * 16 + col;
        #pragma unroll
        for (int kt = 0; kt < 8; ++kt) {
            const float* src = Wh + (size_t)grow * 256 + kt * 32 + quad * 8;
            float4 x0 = *(const float4*)src;
            float4 x1 = *(const float4*)(src + 4);
            bf16x8 f;
            f[0] = (short)f2bf(x0.x); f[1] = (short)f2bf(x0.y);
            f[2] = (short)f2bf(x0.z); f[3] = (short)f2bf(x0.w);
            f[4] = (short)f2bf(x1.x); f[5] = (short)f2bf(x1.y);
            f[6] = (short)f2bf(x1.z); f[7] = (short)f2bf(x1.w);
            wf[g][kt] = f;
        }
    }
    // zero both hbuf parities (h0 = 0 for own AND partner halves)
    for (int u = tid; u < 4224; u += 512) ((unsigned int*)hbuf)[u] = 0;
    __syncthreads();

    float cst[4] = {0.f, 0.f, 0.f, 0.f};
    int jpre = uh * 2 + (w >> 2);                 // pre j-slice for this wave's units
    int tidp = (b2 * 4 + (w & 3)) * 64 + l;       // pre lane index
    size_t rb = (size_t)(dir * 2 + b2) * 513;     // hall region row (x4096 ushorts)
    int rrow = l >> 2, cpart = l & 3;

    // preload pre for st=0
    uint4 pn0, pn1;
    {
        int s0 = dir ? 511 : 0;
        const uint4* pp = (const uint4*)(pre + ((((size_t)(dir * 512 + s0)) * 4 + jpre) * 512 + tidp) * 16);
        pn0 = pp[0]; pn1 = pp[1];
    }

    for (int st = 0; st < 512; ++st) {
        int cur = st & 1;
        unsigned short* hb_cur = hbuf + cur * 4224;
        unsigned short* hb_nxt = hbuf + (cur ^ 1) * 4224;
        uint4 p0 = pn0, p1 = pn1;                // pre(st), prefetched last step
        // prefetch pre(st+1): used a full step later, never drained on critical path
        {
            int stn = (st < 511) ? st + 1 : st;
            int sn = dir ? (511 - stn) : stn;
            const uint4* pp = (const uint4*)(pre + ((((size_t)(dir * 512 + sn)) * 4 + jpre) * 512 + tidp) * 16);
            pn0 = pp[0]; pn1 = pp[1];
        }

        f32x4 acc[4];
        #pragma unroll
        for (int g = 0; g < 4; ++g) acc[g] = (f32x4){0.f, 0.f, 0.f, 0.f};

        // ---- phase A: own-half K MFMAs (own h is already in hb_cur) ----
        #pragma unroll
        for (int k2 = 0; k2 < 4; ++k2) {
            int kt = uh * 4 + k2;
            bf16x8 af = *(const bf16x8*)(hb_cur + col * 264 + kt * 32 + quad * 8);
            #pragma unroll
            for (int g = 0; g < 4; ++g)
                acc[g] = __builtin_amdgcn_mfma_f32_16x16x32_bf16(af, wf[g][kt], acc[g], 0, 0, 0);
        }

        // ---- phase B: detect partner flag(st), load partner 4KB half ----
        if (st > 0) {
            if (tid == 0) {
                unsigned int* fl = flags + ((rb + st) * 2 + (uh ^ 1)) * 32;
                int rnd = 0;
                for (;;) {
                    unsigned int expv = 0u;
                    __hip_atomic_compare_exchange_strong(fl, &expv, 0u,
                        __ATOMIC_RELAXED, __ATOMIC_RELAXED, __HIP_MEMORY_SCOPE_WORKGROUP);
                    if (expv != 0u) break;
                    if (++rnd > (1 << 16)) break;       // guard: fail visibly, no hang
                }
                __hip_atomic_store(&go, st, __ATOMIC_RELAXED, __HIP_MEMORY_SCOPE_WORKGROUP);
            }
            long sg = 0;
            while (__hip_atomic_load(&go, __ATOMIC_RELAXED, __HIP_MEMORY_SCOPE_WORKGROUP) < st) {
                if (++sg > (1L << 20)) break;           // guard: fail visibly, no hang
            }
            asm volatile("" ::: "memory");
            // one-shot plain 8B loads (cold lines, RMW-detected): 512 chunks
            size_t srcb = (rb + st) * 4096 + (size_t)(uh ^ 1) * 2048 + (size_t)tid * 4;
            unsigned long long pv = *(const unsigned long long*)(hall + srcb);
            int prow = tid >> 5, ploc = (tid * 4) & 127;
            *(unsigned long long*)(hb_cur + prow * 264 + (uh ^ 1) * 128 + ploc) = pv;
        }
        lds_barrier();                                  // partner half visible to all waves

        // ---- phase C: partner-half K MFMAs ----
        #pragma unroll
        for (int k2 = 0; k2 < 4; ++k2) {
            int kt = (uh ^ 1) * 4 + k2;
            bf16x8 af = *(const bf16x8*)(hb_cur + col * 264 + kt * 32 + quad * 8);
            #pragma unroll
            for (int g = 0; g < 4; ++g)
                acc[g] = __builtin_amdgcn_mfma_f32_16x16x32_bf16(af, wf[g][kt], acc[g], 0, 0, 0);
        }

        // ---- phase D: z, gates, h(st+1); publish own half; flag ----
        unsigned int pw[8] = {p0.x, p0.y, p0.z, p0.w, p1.x, p1.y, p1.z, p1.w};
        float z[4][4];
        #pragma unroll
        for (int g = 0; g < 4; ++g) {
            #pragma unroll
            for (int r2 = 0; r2 < 2; ++r2) {
                unsigned int u = pw[g * 2 + r2];
                z[g][r2 * 2]     = acc[g][r2 * 2]     + bf2f((unsigned short)(u & 0xffff));
                z[g][r2 * 2 + 1] = acc[g][r2 * 2 + 1] + bf2f((unsigned short)(u >> 16));
            }
        }
        unsigned short hb16[4];
        #pragma unroll
        for (int r = 0; r < 4; ++r) {   // gates i,f,g,o; lane = (batch row quad*4+r, unit uh*128+w*16+col)
            float ci = sigf(z[1][r]) * cst[r] + sigf(z[0][r]) * tanhf_(z[2][r]);
            cst[r] = ci;
            hb16[r] = f2bf(sigf(z[3][r]) * tanhf_(ci));
        }
        // stage own h(st+1) tile into next-parity hbuf (2B LDS writes, wave-local region)
        #pragma unroll
        for (int r = 0; r < 4; ++r)
            hb_nxt[(quad * 4 + r) * 264 + uh * 128 + w * 16 + col] = hb16[r];
        asm volatile("s_waitcnt lgkmcnt(0)" ::: "memory");    // wave's own writes done
        __builtin_amdgcn_sched_barrier(0);
        // readback 8B chunks (same-wave data) and publish to global half-region
        unsigned long long hv = *(const unsigned long long*)
            (hb_nxt + rrow * 264 + uh * 128 + w * 16 + cpart * 4);
        size_t pub = (rb + st + 1) * 4096 + (size_t)uh * 2048 + rrow * 128 + w * 16 + cpart * 4;
        *(unsigned long long*)(hall + pub) = hv;
        // drain publish + full barrier (also orders hb_nxt writes for next iter), then flag
        asm volatile("s_waitcnt vmcnt(0) lgkmcnt(0)" ::: "memory");
        __builtin_amdgcn_s_barrier();
        __builtin_amdgcn_sched_barrier(0);
        if (tid == 0)
            (void)__hip_atomic_exchange(flags + ((rb + st + 1) * 2 + uh) * 32, 1u,
                                        __ATOMIC_RELAXED, __HIP_MEMORY_SCOPE_WORKGROUP);
    }
}

// ============ kernel 4: emissions e[b][s][t] = [hf|hb] . Wt[t] + bt ============
__global__ __launch_bounds__(256) void k_emis(
    const float* __restrict__ Wt, const float* __restrict__ bt, char* __restrict__ ws)
{
    __shared__ float WtL[16 * 528];
    __shared__ unsigned short hrow[16 * 536];
    __shared__ float btL[16];
    int blk = blockIdx.x, tid = threadIdx.x;
    int sbb = blk * 16;
    int s = sbb >> 5, bbase = sbb & 31;     // 16 batch rows per block, fixed s
    int b2 = bbase >> 4;
    const unsigned short* hall = (const unsigned short*)(ws + WS_HALL);
    float* emis = (float*)(ws + WS_EMIS);
    #pragma unroll
    for (int i = 0; i < 8; ++i) {           // Wt 16x512 f32 -> LDS
        int c = tid + i * 256;
        int trow = c >> 7, c128 = c & 127;
        float4 v = *(const float4*)(Wt + (size_t)trow * 512 + c128 * 4);
        *(float4*)(WtL + trow * 528 + c128 * 4) = v;
    }
    #pragma unroll
    for (int i = 0; i < 4; ++i) {           // h rows: [i][0..255]=hf(s), [i][256..511]=hb(s)
        int c = tid + i * 256;
        int row = c >> 6, c6 = c & 63, dsel = c6 >> 5, c16 = c6 & 31;
        int uh = (c16 >> 4) & 1, within = (c16 & 15) * 8;
        size_t base = (dsel == 0)
            ? ((size_t)(b2 * 513) + (size_t)(s + 1)) * 4096
            : ((size_t)((2 + b2) * 513) + (size_t)(512 - s)) * 4096;
        uint4 v = *(const uint4*)(hall + base + (size_t)uh * 2048 + row * 128 + within);
        *(uint4*)(hrow + row * 536 + dsel * 256 + c16 * 8) = v;
    }
    if (tid < 16) btL[tid] = bt[tid];
    __syncthreads();
    int t = tid >> 4, i = tid & 15;
    float acc = btL[t];
    const float* wrow = WtL + t * 528;
    const unsigned short* hr = hrow + i * 536;
    #pragma unroll 8
    for (int k = 0; k < 512; k += 4) {
        uint2 hu = *(const uint2*)(hr + k);
        float4 wv = *(const float4*)(wrow + k);
        acc += bf2f((unsigned short)(hu.x & 0xffff)) * wv.x
             + bf2f((unsigned short)(hu.x >> 16))    * wv.y
             + bf2f((unsigned short)(hu.y & 0xffff)) * wv.z
             + bf2f((unsigned short)(hu.y >> 16))    * wv.w;
    }
    emis[((size_t)(bbase + i) * 512 + s) * 16 + t] = acc;
}

// ============ kernel 5: CRF chunk products (log-semiring, associative) ============
__global__ __launch_bounds__(256) void k_crfc(const float* __restrict__ trans, char* __restrict__ ws)
{
    __shared__ float trL[16 * 17];
    __shared__ float est[16 * 16];
    __shared__ float Pb[2][16 * 17];
    int blk = blockIdx.x, tid = threadIdx.x;
    int b = blk >> 5, c = blk & 31;
    int t = tid >> 4, p = tid & 15;
    const float* emis = (const float*)(ws + WS_EMIS);
    float* chk = (float*)(ws + WS_CHK);
    trL[t * 17 + p] = trans[t * 16 + p];
    est[t * 16 + p] = emis[((size_t)b * 512 + c * 16 + t) * 16 + p];
    __syncthreads();
    float tr[16];
    #pragma unroll
    for (int q = 0; q < 16; ++q) tr[q] = trL[t * 17 + q];
    float out = trL[t * 17 + p] + est[0 * 16 + t];
    Pb[0][t * 17 + p] = out;
    __syncthreads();
    int cur = 0;
    for (int si = 1; si < 16; ++si) {
        float v[16]; float mx = -3.0e38f;
        #pragma unroll
        for (int q = 0; q < 16; ++q) { v[q] = tr[q] + Pb[cur][q * 17 + p]; mx = fmaxf(mx, v[q]); }
        float ss = 0.f;
        #pragma unroll
        for (int q = 0; q < 16; ++q) ss += __expf(v[q] - mx);
        out = est[si * 16 + t] + mx + __logf(ss);
        Pb[1 - cur][t * 17 + p] = out;
        __syncthreads();
        cur = 1 - cur;
    }
    chk[(size_t)(b * 32 + c) * 256 + t * 16 + p] = out;
}

// ============ kernel 6: fold 32 chunk matrices per batch, apply alpha0/stop, emit log_Z ============
__global__ __launch_bounds__(256) void k_crff(
    const float* __restrict__ trans, char* __restrict__ ws, float* __restrict__ out)
{
    __shared__ float Cst[16 * 17];
    __shared__ float Pb[2][16 * 17];
    __shared__ float af[16];
    int b = blockIdx.x, tid = threadIdx.x;
    int t = tid >> 4, p = tid & 15;
    const float* chk = (const float*)(ws + WS_CHK);
    Pb[0][t * 17 + p] = chk[(size_t)(b * 32) * 256 + t * 16 + p];
    __syncthreads();
    int cur = 0;
    for (int ci = 1; ci < 32; ++ci) {
        Cst[t * 17 + p] = chk[(size_t)(b * 32 + ci) * 256 + t * 16 + p];
        __syncthreads();
        float v[16]; float mx = -3.0e38f;
        #pragma unroll
        for (int q = 0; q < 16; ++q) { v[q] = Cst[t * 17 + q] + Pb[cur][q * 17 + p]; mx = fmaxf(mx, v[q]); }
        float ss = 0.f;
        #pragma unroll
        for (int q = 0; q < 16; ++q) ss += __expf(v[q] - mx);
        float outv = mx + __logf(ss);
        Pb[1 - cur][t * 17 + p] = outv;
        __syncthreads();
        cur = 1 - cur;
    }
    float vfin = Pb[cur][t * 17 + p] + ((p == 14) ? 0.0f : -10000.0f);  // alpha0: START=14
    Cst[t * 17 + p] = vfin;
    __syncthreads();
    if (tid < 16) {
        float mx = -3.0e38f;
        for (int q = 0; q < 16; ++q) mx = fmaxf(mx, Cst[tid * 17 + q]);
        float ss = 0.f;
        for (int q = 0; q < 16; ++q) ss += __expf(Cst[tid * 17 + q] - mx);
        af[tid] = mx + __logf(ss) + trans[15 * 16 + tid];               // STOP=15
    }
    __syncthreads();
    if (tid == 0) {
        float mx = -3.0e38f;
        for (int q = 0; q < 16; ++q) mx = fmaxf(mx, af[q]);
        float ss = 0.f;
        for (int q = 0; q < 16; ++q) ss += __expf(af[q] - mx);
        out[b] = mx + __logf(ss);
    }
}

extern "C" void kernel_launch(void* const* d_in, const int* in_sizes, int n_in,
                              void* d_out, int out_size, void* d_ws, size_t ws_size,
                              hipStream_t stream)
{
    const int*   tokens = (const int*)d_in[0];
    const float* embed  = (const float*)d_in[1];
    const float* Wi_f   = (const float*)d_in[2];
    const float* Wh_f   = (const float*)d_in[3];
    const float* bi_f   = (const float*)d_in[4];
    const float* bh_f   = (const float*)d_in[5];
    const float* Wi_b   = (const float*)d_in[6];
    const float* Wh_b   = (const float*)d_in[7];
    const float* bi_b   = (const float*)d_in[8];
    const float* bh_b   = (const float*)d_in[9];
    const float* Wt     = (const float*)d_in[10];
    const float* bt     = (const float*)d_in[11];
    const float* trans  = (const float*)d_in[12];
    char* ws = (char*)d_ws;
    float* out = (float*)d_out;

    hipLaunchKernelGGL(k_prep, dim3(2560), dim3(256), 0, stream,
                       tokens, embed, Wi_f, Wi_b, bi_f, bh_f, bi_b, bh_b, ws);
    hipLaunchKernelGGL(k_pregemm, dim3(4096), dim3(256), 0, stream, ws);
    hipLaunchKernelGGL(k_rec, dim3(128), dim3(512), 0, stream, Wh_f, Wh_b, ws);
    hipLaunchKernelGGL(k_emis, dim3(1024), dim3(256), 0, stream, Wt, bt, ws);
    hipLaunchKernelGGL(k_crfc, dim3(1024), dim3(256), 0, stream, trans, ws);
    hipLaunchKernelGGL(k_crff, dim3(32), dim3(256), 0, stream, trans, ws, out);
}

// Round 8
// 1618.007 us; speedup vs baseline: 2.8619x; 2.8619x over previous
//
#include <hip/hip_runtime.h>
#include <hip/hip_bf16.h>
#include <stdint.h>

typedef __attribute__((ext_vector_type(4))) float f32x4;
typedef __attribute__((ext_vector_type(8))) short bf16x8;

// ---- workspace layout (bytes) ----
#define WS_XBF   0u          // x gathered, bf16 [S=512][B=32][E=256]          = 8388608
#define WS_WIR   8388608u    // Wi permuted rows, bf16 [2048][256]             = 1048576
#define WS_BIAS  9437184u    // bi+bh permuted, f32 [2048]                     = 8192
#define WS_PRE   9445376u    // pre, bf16 [2][512 s][4 slice][512 tid][16]     = 67108864
#define WS_HALL  76554240u   // h halves: [2 dir][2 b2][513 st][2 uh][16 r][128 u] bf16 = 16809984
#define WS_CTL   93364224u   // XCD-team claim control block (16 u32, in gap)
#define WS_EMIS  93368320u   // emissions f32 [32 b][512 s][16 t]              = 1048576
#define WS_CHK   94416896u   // CRF chunk mats f32 [32 b][32 c][16][16]        = 1048576
// flags alias CHK (k_crfc runs after k_rec): u32 [(dir*2+b2)*513+st][2 uh][32 pad]
#define WS_FLG   WS_CHK      // 4*513*2*32*4 = 525312 B < 1 MiB

__device__ __forceinline__ unsigned short f2bf(float x) {
    union { float f; unsigned int u; } v; v.f = x;
    return (unsigned short)((v.u + 0x7FFFu + ((v.u >> 16) & 1u)) >> 16);
}
__device__ __forceinline__ float bf2f(unsigned short b) {
    union { float f; unsigned int u; } v; v.u = ((unsigned int)b) << 16; return v.f;
}
__device__ __forceinline__ unsigned int pack2(float a, float b) {
    return (unsigned int)f2bf(a) | ((unsigned int)f2bf(b) << 16);
}
__device__ __forceinline__ float sigf(float x)  { return 1.0f / (1.0f + __expf(-x)); }
__device__ __forceinline__ float tanhf_(float x){ return 1.0f - 2.0f / (__expf(2.0f * x) + 1.0f); }

// LDS-only barrier: waits lgkmcnt only; in-flight global ops keep flying.
__device__ __forceinline__ void lds_barrier() {
    asm volatile("s_waitcnt lgkmcnt(0)" ::: "memory");
    __builtin_amdgcn_s_barrier();
    __builtin_amdgcn_sched_barrier(0);
}

// ============ kernel 1: gather x -> bf16, permute Wi rows, combine biases, zero h/flags ============
__global__ __launch_bounds__(256) void k_prep(
    const int* __restrict__ tokens, const float* __restrict__ embed,
    const float* __restrict__ Wi_f, const float* __restrict__ Wi_b,
    const float* __restrict__ bi_f, const float* __restrict__ bh_f,
    const float* __restrict__ bi_b, const float* __restrict__ bh_b,
    char* __restrict__ ws)
{
    int blk = blockIdx.x, tid = threadIdx.x;
    unsigned short* xbf  = (unsigned short*)(ws + WS_XBF);
    unsigned short* wir  = (unsigned short*)(ws + WS_WIR);
    float* biasr         = (float*)(ws + WS_BIAS);
    if (blk < 2048) {                       // x gather: 8 rows/block
        int rr = tid >> 5, cc = tid & 31;
        int r = blk * 8 + rr;               // r = s*32+b
        int s = r >> 5, b = r & 31;
        int tok = tokens[b * 512 + s];
        int k = cc * 8;
        const float* src = embed + (size_t)tok * 256 + k;
        float4 a = *(const float4*)src;
        float4 c = *(const float4*)(src + 4);
        uint4 o; o.x = pack2(a.x, a.y); o.y = pack2(a.z, a.w);
        o.z = pack2(c.x, c.y); o.w = pack2(c.z, c.w);
        *(uint4*)(xbf + (size_t)r * 256 + k) = o;
    } else if (blk < 2304) {                // Wi row permute: dest row' = dir*1024 + j*256 + (g*64+hl)
        int rr = tid >> 5, cc = tid & 31;
        int rowp = (blk - 2048) * 8 + rr;   // 0..2047
        int dir = rowp >> 10, q = rowp & 1023;
        int j = q >> 8, rs = q & 255;
        int g = rs >> 6, hl = rs & 63;
        int srow = g * 256 + j * 64 + hl;
        const float* W = dir ? Wi_b : Wi_f;
        int k = cc * 8;
        const float* src = W + (size_t)srow * 256 + k;
        float4 a = *(const float4*)src;
        float4 c = *(const float4*)(src + 4);
        uint4 o; o.x = pack2(a.x, a.y); o.y = pack2(a.z, a.w);
        o.z = pack2(c.x, c.y); o.w = pack2(c.z, c.w);
        *(uint4*)(wir + (size_t)rowp * 256 + k) = o;
        if (cc == 0)
            biasr[rowp] = dir ? (bi_b[srow] + bh_b[srow]) : (bi_f[srow] + bh_f[srow]);
    } else {                                // zero h buffers (slot 0 = h0 = 0), ctl, flags
        if (blk == 2304 && tid < 16)
            ((unsigned int*)(ws + WS_CTL))[tid] = 0u;
        if (blk == 2305) {                  // zero the step-ready flag array
            unsigned int* flg = (unsigned int*)(ws + WS_FLG);
            for (int u = tid; u < 4 * 513 * 2 * 32; u += 256) flg[u] = 0u;
        }
        size_t g = (size_t)(blk - 2304) * 256 + tid;
        uint4* hall4 = (uint4*)(ws + WS_HALL);
        uint4 z; z.x = 0u; z.y = 0u; z.z = 0u; z.w = 0u;
        for (size_t u = g; u < 1050624u; u += 65536u)     // 16,809,984 B / 16
            hall4[u] = z;
    }
}

// ============ kernel 2: pre = x*Wi^T + bias, written in recurrence-lane-private layout ============
__global__ __launch_bounds__(256) void k_pregemm(char* __restrict__ ws)
{
    __shared__ unsigned short Asb[128 * 136];
    __shared__ unsigned short Bsb[64 * 136];
    const unsigned short* xbf = (const unsigned short*)(ws + WS_XBF);
    const unsigned short* wir = (const unsigned short*)(ws + WS_WIR);
    const float* biasr        = (const float*)(ws + WS_BIAS);
    unsigned short* pre       = (unsigned short*)(ws + WS_PRE);
    int blk = blockIdx.x, tid = threadIdx.x;
    int mb = blk >> 5, nb = blk & 31;
    int Mbase = mb * 128, Nbase = nb * 64;
    int w = tid >> 6, l = tid & 63, col = l & 15, quad = l >> 4;
    f32x4 acc[4][2];
    #pragma unroll
    for (int a = 0; a < 4; ++a)
        #pragma unroll
        for (int b = 0; b < 2; ++b) acc[a][b] = (f32x4){0.f, 0.f, 0.f, 0.f};

    for (int kh = 0; kh < 2; ++kh) {
        __syncthreads();
        #pragma unroll
        for (int i = 0; i < 8; ++i) {       // A half-tile 128x128 bf16
            int c = tid + i * 256;
            int row = c >> 4, c16 = c & 15;
            uint4 v = *(const uint4*)(xbf + ((size_t)(Mbase + row) * 256 + kh * 128 + c16 * 8));
            *(uint4*)(Asb + row * 136 + c16 * 8) = v;
        }
        #pragma unroll
        for (int i = 0; i < 4; ++i) {       // B half-tile 64x128 bf16
            int c = tid + i * 256;
            int row = c >> 4, c16 = c & 15;
            uint4 v = *(const uint4*)(wir + ((size_t)(Nbase + row) * 256 + kh * 128 + c16 * 8));
            *(uint4*)(Bsb + row * 136 + c16 * 8) = v;
        }
        __syncthreads();
        int mhalf = w >> 1, nh = w & 1;
        #pragma unroll
        for (int kt = 0; kt < 4; ++kt) {
            bf16x8 bfr[2];
            #pragma unroll
            for (int nn = 0; nn < 2; ++nn)
                bfr[nn] = *(const bf16x8*)(Bsb + (16 * (nh * 2 + nn) + col) * 136 + kt * 32 + quad * 8);
            #pragma unroll
            for (int mm = 0; mm < 4; ++mm) {
                bf16x8 afr = *(const bf16x8*)(Asb + (16 * (mhalf * 4 + mm) + col) * 136 + kt * 32 + quad * 8);
                #pragma unroll
                for (int nn = 0; nn < 2; ++nn)
                    acc[mm][nn] = __builtin_amdgcn_mfma_f32_16x16x32_bf16(afr, bfr[nn], acc[mm][nn], 0, 0, 0);
            }
        }
    }
    // epilogue: + bias, bf16, permuted store matching recurrence lane layout
    #pragma unroll
    for (int mm = 0; mm < 4; ++mm) {
        int m_t = (w >> 1) * 4 + mm;
        int s = (Mbase >> 5) + (m_t >> 1);
        int bhalf = m_t & 1;
        #pragma unroll
        for (int nn = 0; nn < 2; ++nn) {
            int ncol = Nbase + 16 * ((w & 1) * 2 + nn) + col;
            int dir = ncol >> 10, j = (ncol >> 8) & 3, r = ncol & 255;
            int g = r >> 6, hl16 = (r >> 4) & 3;
            int tidp = (bhalf * 4 + hl16) * 64 + l;
            float bv = biasr[ncol];
            f32x4 a = acc[mm][nn];
            uint2 o;
            o.x = pack2(a[0] + bv, a[1] + bv);
            o.y = pack2(a[2] + bv, a[3] + bv);
            size_t off = (((size_t)(dir * 512 + s) * 4 + j) * 512 + tidp) * 16 + g * 4;
            *(uint2*)(pre + off) = o;
        }
    }
}

// ============ kernel 3: persistent bidirectional LSTM recurrence ============
// Round-8 = r7's pairwise structure + RULE #20 FIX. r7's VGPR_Count=88 proved the
// persistent weights were demoted to scratch: phases A/C indexed wf[g][uh*4+k2]
// with RUNTIME uh -> LLVM can't prove static indices -> scratch allocation ->
// every MFMA reloaded its B-operand from memory (the 3x regression). Fix: weights
// split at LOAD time (runtime uh in the ADDRESS only) into wfO[4][4] (own-half K)
// and wfP[4][4] (partner-half K); phases A/C index them with compile-time k2 only.
// Structure unchanged from r7 (passed correctness): (dir x batch-half x unit-half)
// blocks, pairwise 4KB exchange, own-half MFMAs overlap the partner-flag poll,
// r6-proven protocol pieces (1 CAS poller + LDS fanout, one-shot cold-line loads,
// plain publish + vmcnt drain + barrier + one flag swap).
__global__ __launch_bounds__(512, 2) void k_rec(
    const float* __restrict__ Wh_f, const float* __restrict__ Wh_b, char* __restrict__ ws)
{
    __shared__ unsigned short hbuf[2 * 16 * 264];   // [parity][16 rows][256 units +8 pad]
    __shared__ char stpad[71680];                   // occupancy limiter -> 1 block/CU
    __shared__ int sRole;
    __shared__ int go;
    int tid = threadIdx.x;

    // ---- XCD team claim (proven r1-r7) ----
    if (tid == 0) {
        ((volatile char*)stpad)[0] = 0;
        go = 0;
        int xcd;
        asm volatile("s_getreg_b32 %0, hwreg(HW_REG_XCC_ID)" : "=s"(xcd));
        xcd &= 7;
        unsigned int* ctl = (unsigned int*)(ws + WS_CTL);
        unsigned int slot = __hip_atomic_fetch_add(&ctl[xcd], 1u,
                              __ATOMIC_RELAXED, __HIP_MEMORY_SCOPE_AGENT);
        int role = -1;
        if (slot < 8u) {
            if (slot == 7u) {
                unsigned int expv = 0u;
                __hip_atomic_compare_exchange_strong(&ctl[8], &expv, (unsigned int)(xcd + 1),
                    __ATOMIC_RELAXED, __ATOMIC_RELAXED, __HIP_MEMORY_SCOPE_AGENT);
            }
            unsigned int ts; long gc = 0;
            do {
                ts = __hip_atomic_fetch_add(&ctl[8], 0u,
                        __ATOMIC_RELAXED, __HIP_MEMORY_SCOPE_AGENT);
            } while (ts == 0u && ++gc < (1L << 26));
            if (ts == (unsigned int)(xcd + 1)) role = (int)slot;
        }
        sRole = role;
    }
    __syncthreads();
    int role = sRole;
    if (role < 0) return;
    int dir = role >> 2, b2 = (role >> 1) & 1, uh = role & 1;

    int w = tid >> 6, l = tid & 63, col = l & 15, quad = l >> 4;
    const float* Wh = dir ? Wh_b : Wh_f;
    const unsigned short* pre = (const unsigned short*)(ws + WS_PRE);
    unsigned short* hall      = (unsigned short*)(ws + WS_HALL);
    unsigned int* flags       = (unsigned int*)(ws + WS_FLG);

    // persistent weight B-fragments, SPLIT BY K-HALF AT LOAD TIME (rule #20 fix):
    // wfO[g][k2] = Wh[grow][ (uh*4+k2)*32 ... ]   (own-half K tiles)
    // wfP[g][k2] = Wh[grow][((uh^1)*4+k2)*32 ...] (partner-half K tiles)
    // runtime uh appears only in ADDRESSES; array indices are compile-time.
    bf16x8 wfO[4][4], wfP[4][4];
    #pragma unroll
    for (int g = 0; g < 4; ++g) {
        int grow = g * 256 + uh * 128 + w * 16 + col;
        const float* rowp_ = Wh + (size_t)grow * 256 + quad * 8;
        #pragma unroll
        for (int k2 = 0; k2 < 4; ++k2) {
            {
                const float* src = rowp_ + (uh * 4 + k2) * 32;
                float4 x0 = *(const float4*)src;
                float4 x1 = *(const float4*)(src + 4);
                bf16x8 f;
                f[0] = (short)f2bf(x0.x); f[1] = (short)f2bf(x0.y);
                f[2] = (short)f2bf(x0.z); f[3] = (short)f2bf(x0.w);
                f[4] = (short)f2bf(x1.x); f[5] = (short)f2bf(x1.y);
                f[6] = (short)f2bf(x1.z); f[7] = (short)f2bf(x1.w);
                wfO[g][k2] = f;
            }
            {
                const float* src = rowp_ + ((uh ^ 1) * 4 + k2) * 32;
                float4 x0 = *(const float4*)src;
                float4 x1 = *(const float4*)(src + 4);
                bf16x8 f;
                f[0] = (short)f2bf(x0.x); f[1] = (short)f2bf(x0.y);
                f[2] = (short)f2bf(x0.z); f[3] = (short)f2bf(x0.w);
                f[4] = (short)f2bf(x1.x); f[5] = (short)f2bf(x1.y);
                f[6] = (short)f2bf(x1.z); f[7] = (short)f2bf(x1.w);
                wfP[g][k2] = f;
            }
        }
    }
    // zero both hbuf parities (h0 = 0 for own AND partner halves)
    for (int u = tid; u < 4224; u += 512) ((unsigned int*)hbuf)[u] = 0;
    __syncthreads();

    float cst[4] = {0.f, 0.f, 0.f, 0.f};
    int jpre = uh * 2 + (w >> 2);                 // pre j-slice for this wave's units
    int tidp = (b2 * 4 + (w & 3)) * 64 + l;       // pre lane index
    size_t rb = (size_t)(dir * 2 + b2) * 513;     // hall region row (x4096 ushorts)
    int rrow = l >> 2, cpart = l & 3;
    int ownKB = uh * 128;                         // LDS byte-col base of own K half (ushorts)
    int prtKB = (uh ^ 1) * 128;

    // preload pre for st=0
    uint4 pn0, pn1;
    {
        int s0 = dir ? 511 : 0;
        const uint4* pp = (const uint4*)(pre + ((((size_t)(dir * 512 + s0)) * 4 + jpre) * 512 + tidp) * 16);
        pn0 = pp[0]; pn1 = pp[1];
    }

    for (int st = 0; st < 512; ++st) {
        int cur = st & 1;
        unsigned short* hb_cur = hbuf + cur * 4224;
        unsigned short* hb_nxt = hbuf + (cur ^ 1) * 4224;
        uint4 p0 = pn0, p1 = pn1;                // pre(st), prefetched last step
        // prefetch pre(st+1): used a full step later, never drained on critical path
        {
            int stn = (st < 511) ? st + 1 : st;
            int sn = dir ? (511 - stn) : stn;
            const uint4* pp = (const uint4*)(pre + ((((size_t)(dir * 512 + sn)) * 4 + jpre) * 512 + tidp) * 16);
            pn0 = pp[0]; pn1 = pp[1];
        }

        f32x4 acc[4];
        #pragma unroll
        for (int g = 0; g < 4; ++g) acc[g] = (f32x4){0.f, 0.f, 0.f, 0.f};

        // ---- phase A: own-half K MFMAs (own h already in hb_cur; wfO compile-time idx) ----
        #pragma unroll
        for (int k2 = 0; k2 < 4; ++k2) {
            bf16x8 af = *(const bf16x8*)(hb_cur + col * 264 + ownKB + k2 * 32 + quad * 8);
            #pragma unroll
            for (int g = 0; g < 4; ++g)
                acc[g] = __builtin_amdgcn_mfma_f32_16x16x32_bf16(af, wfO[g][k2], acc[g], 0, 0, 0);
        }

        // ---- phase B: detect partner flag(st), load partner 4KB half ----
        if (st > 0) {
            if (tid == 0) {
                unsigned int* fl = flags + ((rb + st) * 2 + (uh ^ 1)) * 32;
                int rnd = 0;
                for (;;) {
                    unsigned int expv = 0u;
                    __hip_atomic_compare_exchange_strong(fl, &expv, 0u,
                        __ATOMIC_RELAXED, __ATOMIC_RELAXED, __HIP_MEMORY_SCOPE_WORKGROUP);
                    if (expv != 0u) break;
                    if (++rnd > (1 << 16)) break;       // guard: fail visibly, no hang
                }
                __hip_atomic_store(&go, st, __ATOMIC_RELAXED, __HIP_MEMORY_SCOPE_WORKGROUP);
            }
            long sg = 0;
            while (__hip_atomic_load(&go, __ATOMIC_RELAXED, __HIP_MEMORY_SCOPE_WORKGROUP) < st) {
                if (++sg > (1L << 20)) break;           // guard: fail visibly, no hang
            }
            asm volatile("" ::: "memory");
            // one-shot plain 8B loads (cold lines, RMW-detected): 512 chunks
            size_t srcb = (rb + st) * 4096 + (size_t)(uh ^ 1) * 2048 + (size_t)tid * 4;
            unsigned long long pv = *(const unsigned long long*)(hall + srcb);
            int prow = tid >> 5, ploc = (tid * 4) & 127;
            *(unsigned long long*)(hb_cur + prow * 264 + prtKB + ploc) = pv;
        }
        lds_barrier();                                  // partner half visible to all waves

        // ---- phase C: partner-half K MFMAs (wfP compile-time idx) ----
        #pragma unroll
        for (int k2 = 0; k2 < 4; ++k2) {
            bf16x8 af = *(const bf16x8*)(hb_cur + col * 264 + prtKB + k2 * 32 + quad * 8);
            #pragma unroll
            for (int g = 0; g < 4; ++g)
                acc[g] = __builtin_amdgcn_mfma_f32_16x16x32_bf16(af, wfP[g][k2], acc[g], 0, 0, 0);
        }

        // ---- phase D: z, gates, h(st+1); publish own half; flag ----
        unsigned int pw[8] = {p0.x, p0.y, p0.z, p0.w, p1.x, p1.y, p1.z, p1.w};
        float z[4][4];
        #pragma unroll
        for (int g = 0; g < 4; ++g) {
            #pragma unroll
            for (int r2 = 0; r2 < 2; ++r2) {
                unsigned int u = pw[g * 2 + r2];
                z[g][r2 * 2]     = acc[g][r2 * 2]     + bf2f((unsigned short)(u & 0xffff));
                z[g][r2 * 2 + 1] = acc[g][r2 * 2 + 1] + bf2f((unsigned short)(u >> 16));
            }
        }
        unsigned short hb16[4];
        #pragma unroll
        for (int r = 0; r < 4; ++r) {   // gates i,f,g,o; lane = (batch row quad*4+r, unit uh*128+w*16+col)
            float ci = sigf(z[1][r]) * cst[r] + sigf(z[0][r]) * tanhf_(z[2][r]);
            cst[r] = ci;
            hb16[r] = f2bf(sigf(z[3][r]) * tanhf_(ci));
        }
        // stage own h(st+1) tile into next-parity hbuf (2B LDS writes, wave-local region)
        #pragma unroll
        for (int r = 0; r < 4; ++r)
            hb_nxt[(quad * 4 + r) * 264 + ownKB + w * 16 + col] = hb16[r];
        asm volatile("s_waitcnt lgkmcnt(0)" ::: "memory");    // wave's own writes done
        __builtin_amdgcn_sched_barrier(0);
        // readback 8B chunks (same-wave data) and publish to global half-region
        unsigned long long hv = *(const unsigned long long*)
            (hb_nxt + rrow * 264 + ownKB + w * 16 + cpart * 4);
        size_t pub = (rb + st + 1) * 4096 + (size_t)uh * 2048 + rrow * 128 + w * 16 + cpart * 4;
        *(unsigned long long*)(hall + pub) = hv;
        // drain publish + full barrier (also orders hb_nxt writes for next iter), then flag
        asm volatile("s_waitcnt vmcnt(0) lgkmcnt(0)" ::: "memory");
        __builtin_amdgcn_s_barrier();
        __builtin_amdgcn_sched_barrier(0);
        if (tid == 0)
            (void)__hip_atomic_exchange(flags + ((rb + st + 1) * 2 + uh) * 32, 1u,
                                        __ATOMIC_RELAXED, __HIP_MEMORY_SCOPE_WORKGROUP);
    }
}

// ============ kernel 4: emissions e[b][s][t] = [hf|hb] . Wt[t] + bt ============
__global__ __launch_bounds__(256) void k_emis(
    const float* __restrict__ Wt, const float* __restrict__ bt, char* __restrict__ ws)
{
    __shared__ float WtL[16 * 528];
    __shared__ unsigned short hrow[16 * 536];
    __shared__ float btL[16];
    int blk = blockIdx.x, tid = threadIdx.x;
    int sbb = blk * 16;
    int s = sbb >> 5, bbase = sbb & 31;     // 16 batch rows per block, fixed s
    int b2 = bbase >> 4;
    const unsigned short* hall = (const unsigned short*)(ws + WS_HALL);
    float* emis = (float*)(ws + WS_EMIS);
    #pragma unroll
    for (int i = 0; i < 8; ++i) {           // Wt 16x512 f32 -> LDS
        int c = tid + i * 256;
        int trow = c >> 7, c128 = c & 127;
        float4 v = *(const float4*)(Wt + (size_t)trow * 512 + c128 * 4);
        *(float4*)(WtL + trow * 528 + c128 * 4) = v;
    }
    #pragma unroll
    for (int i = 0; i < 4; ++i) {           // h rows: [i][0..255]=hf(s), [i][256..511]=hb(s)
        int c = tid + i * 256;
        int row = c >> 6, c6 = c & 63, dsel = c6 >> 5, c16 = c6 & 31;
        int uh = (c16 >> 4) & 1, within = (c16 & 15) * 8;
        size_t base = (dsel == 0)
            ? ((size_t)(b2 * 513) + (size_t)(s + 1)) * 4096
            : ((size_t)((2 + b2) * 513) + (size_t)(512 - s)) * 4096;
        uint4 v = *(const uint4*)(hall + base + (size_t)uh * 2048 + row * 128 + within);
        *(uint4*)(hrow + row * 536 + dsel * 256 + c16 * 8) = v;
    }
    if (tid < 16) btL[tid] = bt[tid];
    __syncthreads();
    int t = tid >> 4, i = tid & 15;
    float acc = btL[t];
    const float* wrow = WtL + t * 528;
    const unsigned short* hr = hrow + i * 536;
    #pragma unroll 8
    for (int k = 0; k < 512; k += 4) {
        uint2 hu = *(const uint2*)(hr + k);
        float4 wv = *(const float4*)(wrow + k);
        acc += bf2f((unsigned short)(hu.x & 0xffff)) * wv.x
             + bf2f((unsigned short)(hu.x >> 16))    * wv.y
             + bf2f((unsigned short)(hu.y & 0xffff)) * wv.z
             + bf2f((unsigned short)(hu.y >> 16))    * wv.w;
    }
    emis[((size_t)(bbase + i) * 512 + s) * 16 + t] = acc;
}

// ============ kernel 5: CRF chunk products (log-semiring, associative) ============
__global__ __launch_bounds__(256) void k_crfc(const float* __restrict__ trans, char* __restrict__ ws)
{
    __shared__ float trL[16 * 17];
    __shared__ float est[16 * 16];
    __shared__ float Pb[2][16 * 17];
    int blk = blockIdx.x, tid = threadIdx.x;
    int b = blk >> 5, c = blk & 31;
    int t = tid >> 4, p = tid & 15;
    const float* emis = (const float*)(ws + WS_EMIS);
    float* chk = (float*)(ws + WS_CHK);
    trL[t * 17 + p] = trans[t * 16 + p];
    est[t * 16 + p] = emis[((size_t)b * 512 + c * 16 + t) * 16 + p];
    __syncthreads();
    float tr[16];
    #pragma unroll
    for (int q = 0; q < 16; ++q) tr[q] = trL[t * 17 + q];
    float out = trL[t * 17 + p] + est[0 * 16 + t];
    Pb[0][t * 17 + p] = out;
    __syncthreads();
    int cur = 0;
    for (int si = 1; si < 16; ++si) {
        float v[16]; float mx = -3.0e38f;
        #pragma unroll
        for (int q = 0; q < 16; ++q) { v[q] = tr[q] + Pb[cur][q * 17 + p]; mx = fmaxf(mx, v[q]); }
        float ss = 0.f;
        #pragma unroll
        for (int q = 0; q < 16; ++q) ss += __expf(v[q] - mx);
        out = est[si * 16 + t] + mx + __logf(ss);
        Pb[1 - cur][t * 17 + p] = out;
        __syncthreads();
        cur = 1 - cur;
    }
    chk[(size_t)(b * 32 + c) * 256 + t * 16 + p] = out;
}

// ============ kernel 6: fold 32 chunk matrices per batch, apply alpha0/stop, emit log_Z ============
__global__ __launch_bounds__(256) void k_crff(
    const float* __restrict__ trans, char* __restrict__ ws, float* __restrict__ out)
{
    __shared__ float Cst[16 * 17];
    __shared__ float Pb[2][16 * 17];
    __shared__ float af[16];
    int b = blockIdx.x, tid = threadIdx.x;
    int t = tid >> 4, p = tid & 15;
    const float* chk = (const float*)(ws + WS_CHK);
    Pb[0][t * 17 + p] = chk[(size_t)(b * 32) * 256 + t * 16 + p];
    __syncthreads();
    int cur = 0;
    for (int ci = 1; ci < 32; ++ci) {
        Cst[t * 17 + p] = chk[(size_t)(b * 32 + ci) * 256 + t * 16 + p];
        __syncthreads();
        float v[16]; float mx = -3.0e38f;
        #pragma unroll
        for (int q = 0; q < 16; ++q) { v[q] = Cst[t * 17 + q] + Pb[cur][q * 17 + p]; mx = fmaxf(mx, v[q]); }
        float ss = 0.f;
        #pragma unroll
        for (int q = 0; q < 16; ++q) ss += __expf(v[q] - mx);
        float outv = mx + __logf(ss);
        Pb[1 - cur][t * 17 + p] = outv;
        __syncthreads();
        cur = 1 - cur;
    }
    float vfin = Pb[cur][t * 17 + p] + ((p == 14) ? 0.0f : -10000.0f);  // alpha0: START=14
    Cst[t * 17 + p] = vfin;
    __syncthreads();
    if (tid < 16) {
        float mx = -3.0e38f;
        for (int q = 0; q < 16; ++q) mx = fmaxf(mx, Cst[tid * 17 + q]);
        float ss = 0.f;
        for (int q = 0; q < 16; ++q) ss += __expf(Cst[tid * 17 + q] - mx);
        af[tid] = mx + __logf(ss) + trans[15 * 16 + tid];               // STOP=15
    }
    __syncthreads();
    if (tid == 0) {
        float mx = -3.0e38f;
        for (int q = 0; q < 16; ++q) mx = fmaxf(mx, af[q]);
        float ss = 0.f;
        for (int q = 0; q < 16; ++q) ss += __expf(af[q] - mx);
        out[b] = mx + __logf(ss);
    }
}

extern "C" void kernel_launch(void* const* d_in, const int* in_sizes, int n_in,
                              void* d_out, int out_size, void* d_ws, size_t ws_size,
                              hipStream_t stream)
{
    const int*   tokens = (const int*)d_in[0];
    const float* embed  = (const float*)d_in[1];
    const float* Wi_f   = (const float*)d_in[2];
    const float* Wh_f   = (const float*)d_in[3];
    const float* bi_f   = (const float*)d_in[4];
    const float* bh_f   = (const float*)d_in[5];
    const float* Wi_b   = (const float*)d_in[6];
    const float* Wh_b   = (const float*)d_in[7];
    const float* bi_b   = (const float*)d_in[8];
    const float* bh_b   = (const float*)d_in[9];
    const float* Wt     = (const float*)d_in[10];
    const float* bt     = (const float*)d_in[11];
    const float* trans  = (const float*)d_in[12];
    char* ws = (char*)d_ws;
    float* out = (float*)d_out;

    hipLaunchKernelGGL(k_prep, dim3(2560), dim3(256), 0, stream,
                       tokens, embed, Wi_f, Wi_b, bi_f, bh_f, bi_b, bh_b, ws);
    hipLaunchKernelGGL(k_pregemm, dim3(4096), dim3(256), 0, stream, ws);
    hipLaunchKernelGGL(k_rec, dim3(128), dim3(512), 0, stream, Wh_f, Wh_b, ws);
    hipLaunchKernelGGL(k_emis, dim3(1024), dim3(256), 0, stream, Wt, bt, ws);
    hipLaunchKernelGGL(k_crfc, dim3(1024), dim3(256), 0, stream, trans, ws);
    hipLaunchKernelGGL(k_crff, dim3(32), dim3(256), 0, stream, trans, ws, out);
}

// Round 9
// 1613.951 us; speedup vs baseline: 2.8691x; 1.0025x over previous
//
#include <hip/hip_runtime.h>
#include <hip/hip_bf16.h>
#include <stdint.h>

typedef __attribute__((ext_vector_type(4))) float f32x4;
typedef __attribute__((ext_vector_type(8))) short bf16x8;

// ---- workspace layout (bytes) ----
#define WS_XBF   0u          // x gathered, bf16 [S=512][B=32][E=256]          = 8388608
#define WS_WIR   8388608u    // Wi permuted rows, bf16 [2048][256]             = 1048576
#define WS_BIAS  9437184u    // bi+bh permuted, f32 [2048]                     = 8192
#define WS_PRE   9445376u    // pre, bf16 [2][512 s][4 slice][512 tid][16]     = 67108864
#define WS_HALL  76554240u   // h halves: [2 dir][2 b2][513 st][2 uh][16 r][128 u] bf16 = 16809984
#define WS_CTL   93364224u   // XCD-team claim control block (16 u32, in gap); ctl[9] = done counter
#define WS_EMIS  93368320u   // emissions f32 [32 b][512 s][16 t]              = 1048576
#define WS_CHK   94416896u   // CRF chunk mats f32 [32 b][32 c][16][16]        = 1048576
// flags alias CHK (k_crfc runs after k_rec): u32 [(dir*2+b2)*513+st][2 uh][32 pad]
#define WS_FLG   WS_CHK      // 4*513*2*32*4 = 525312 B < 1 MiB

__device__ __forceinline__ unsigned short f2bf(float x) {
    union { float f; unsigned int u; } v; v.f = x;
    return (unsigned short)((v.u + 0x7FFFu + ((v.u >> 16) & 1u)) >> 16);
}
__device__ __forceinline__ float bf2f(unsigned short b) {
    union { float f; unsigned int u; } v; v.u = ((unsigned int)b) << 16; return v.f;
}
__device__ __forceinline__ unsigned int pack2(float a, float b) {
    return (unsigned int)f2bf(a) | ((unsigned int)f2bf(b) << 16);
}
__device__ __forceinline__ float sigf(float x)  { return 1.0f / (1.0f + __expf(-x)); }
__device__ __forceinline__ float tanhf_(float x){ return 1.0f - 2.0f / (__expf(2.0f * x) + 1.0f); }

// LDS-only barrier: waits lgkmcnt only; in-flight global ops keep flying.
__device__ __forceinline__ void lds_barrier() {
    asm volatile("s_waitcnt lgkmcnt(0)" ::: "memory");
    __builtin_amdgcn_s_barrier();
    __builtin_amdgcn_sched_barrier(0);
}

// ============ kernel 1: gather x -> bf16, permute Wi rows, combine biases, zero h/flags ============
__global__ __launch_bounds__(256) void k_prep(
    const int* __restrict__ tokens, const float* __restrict__ embed,
    const float* __restrict__ Wi_f, const float* __restrict__ Wi_b,
    const float* __restrict__ bi_f, const float* __restrict__ bh_f,
    const float* __restrict__ bi_b, const float* __restrict__ bh_b,
    char* __restrict__ ws)
{
    int blk = blockIdx.x, tid = threadIdx.x;
    unsigned short* xbf  = (unsigned short*)(ws + WS_XBF);
    unsigned short* wir  = (unsigned short*)(ws + WS_WIR);
    float* biasr         = (float*)(ws + WS_BIAS);
    if (blk < 2048) {                       // x gather: 8 rows/block
        int rr = tid >> 5, cc = tid & 31;
        int r = blk * 8 + rr;               // r = s*32+b
        int s = r >> 5, b = r & 31;
        int tok = tokens[b * 512 + s];
        int k = cc * 8;
        const float* src = embed + (size_t)tok * 256 + k;
        float4 a = *(const float4*)src;
        float4 c = *(const float4*)(src + 4);
        uint4 o; o.x = pack2(a.x, a.y); o.y = pack2(a.z, a.w);
        o.z = pack2(c.x, c.y); o.w = pack2(c.z, c.w);
        *(uint4*)(xbf + (size_t)r * 256 + k) = o;
    } else if (blk < 2304) {                // Wi row permute: dest row' = dir*1024 + j*256 + (g*64+hl)
        int rr = tid >> 5, cc = tid & 31;
        int rowp = (blk - 2048) * 8 + rr;   // 0..2047
        int dir = rowp >> 10, q = rowp & 1023;
        int j = q >> 8, rs = q & 255;
        int g = rs >> 6, hl = rs & 63;
        int srow = g * 256 + j * 64 + hl;
        const float* W = dir ? Wi_b : Wi_f;
        int k = cc * 8;
        const float* src = W + (size_t)srow * 256 + k;
        float4 a = *(const float4*)src;
        float4 c = *(const float4*)(src + 4);
        uint4 o; o.x = pack2(a.x, a.y); o.y = pack2(a.z, a.w);
        o.z = pack2(c.x, c.y); o.w = pack2(c.z, c.w);
        *(uint4*)(wir + (size_t)rowp * 256 + k) = o;
        if (cc == 0)
            biasr[rowp] = dir ? (bi_b[srow] + bh_b[srow]) : (bi_f[srow] + bh_f[srow]);
    } else {                                // zero h buffers (slot 0 = h0 = 0), ctl, flags
        if (blk == 2304 && tid < 16)
            ((unsigned int*)(ws + WS_CTL))[tid] = 0u;
        if (blk == 2305) {                  // zero the step-ready flag array
            unsigned int* flg = (unsigned int*)(ws + WS_FLG);
            for (int u = tid; u < 4 * 513 * 2 * 32; u += 256) flg[u] = 0u;
        }
        size_t g = (size_t)(blk - 2304) * 256 + tid;
        uint4* hall4 = (uint4*)(ws + WS_HALL);
        uint4 z; z.x = 0u; z.y = 0u; z.z = 0u; z.w = 0u;
        for (size_t u = g; u < 1050624u; u += 65536u)     // 16,809,984 B / 16
            hall4[u] = z;
    }
}

// ============ kernel 2: pre = x*Wi^T + bias, written in recurrence-lane-private layout ============
__global__ __launch_bounds__(256) void k_pregemm(char* __restrict__ ws)
{
    __shared__ unsigned short Asb[128 * 136];
    __shared__ unsigned short Bsb[64 * 136];
    const unsigned short* xbf = (const unsigned short*)(ws + WS_XBF);
    const unsigned short* wir = (const unsigned short*)(ws + WS_WIR);
    const float* biasr        = (const float*)(ws + WS_BIAS);
    unsigned short* pre       = (unsigned short*)(ws + WS_PRE);
    int blk = blockIdx.x, tid = threadIdx.x;
    int mb = blk >> 5, nb = blk & 31;
    int Mbase = mb * 128, Nbase = nb * 64;
    int w = tid >> 6, l = tid & 63, col = l & 15, quad = l >> 4;
    f32x4 acc[4][2];
    #pragma unroll
    for (int a = 0; a < 4; ++a)
        #pragma unroll
        for (int b = 0; b < 2; ++b) acc[a][b] = (f32x4){0.f, 0.f, 0.f, 0.f};

    for (int kh = 0; kh < 2; ++kh) {
        __syncthreads();
        #pragma unroll
        for (int i = 0; i < 8; ++i) {       // A half-tile 128x128 bf16
            int c = tid + i * 256;
            int row = c >> 4, c16 = c & 15;
            uint4 v = *(const uint4*)(xbf + ((size_t)(Mbase + row) * 256 + kh * 128 + c16 * 8));
            *(uint4*)(Asb + row * 136 + c16 * 8) = v;
        }
        #pragma unroll
        for (int i = 0; i < 4; ++i) {       // B half-tile 64x128 bf16
            int c = tid + i * 256;
            int row = c >> 4, c16 = c & 15;
            uint4 v = *(const uint4*)(wir + ((size_t)(Nbase + row) * 256 + kh * 128 + c16 * 8));
            *(uint4*)(Bsb + row * 136 + c16 * 8) = v;
        }
        __syncthreads();
        int mhalf = w >> 1, nh = w & 1;
        #pragma unroll
        for (int kt = 0; kt < 4; ++kt) {
            bf16x8 bfr[2];
            #pragma unroll
            for (int nn = 0; nn < 2; ++nn)
                bfr[nn] = *(const bf16x8*)(Bsb + (16 * (nh * 2 + nn) + col) * 136 + kt * 32 + quad * 8);
            #pragma unroll
            for (int mm = 0; mm < 4; ++mm) {
                bf16x8 afr = *(const bf16x8*)(Asb + (16 * (mhalf * 4 + mm) + col) * 136 + kt * 32 + quad * 8);
                #pragma unroll
                for (int nn = 0; nn < 2; ++nn)
                    acc[mm][nn] = __builtin_amdgcn_mfma_f32_16x16x32_bf16(afr, bfr[nn], acc[mm][nn], 0, 0, 0);
            }
        }
    }
    // epilogue: + bias, bf16, permuted store matching recurrence lane layout
    #pragma unroll
    for (int mm = 0; mm < 4; ++mm) {
        int m_t = (w >> 1) * 4 + mm;
        int s = (Mbase >> 5) + (m_t >> 1);
        int bhalf = m_t & 1;
        #pragma unroll
        for (int nn = 0; nn < 2; ++nn) {
            int ncol = Nbase + 16 * ((w & 1) * 2 + nn) + col;
            int dir = ncol >> 10, j = (ncol >> 8) & 3, r = ncol & 255;
            int g = r >> 6, hl16 = (r >> 4) & 3;
            int tidp = (bhalf * 4 + hl16) * 64 + l;
            float bv = biasr[ncol];
            f32x4 a = acc[mm][nn];
            uint2 o;
            o.x = pack2(a[0] + bv, a[1] + bv);
            o.y = pack2(a[2] + bv, a[3] + bv);
            size_t off = (((size_t)(dir * 512 + s) * 4 + j) * 512 + tidp) * 16 + g * 4;
            *(uint2*)(pre + off) = o;
        }
    }
}

// ============ kernel 3: persistent bidirectional LSTM recurrence ============
// Round-9 = r8 byte-identical protocol + DVFS CLOCK-PIN EXPERIMENT.
// r0-r8 post-mortem: eight protocol designs, one invariant 6630 cy/step. Serial-chain
// arithmetic @2.4GHz sums to ~2500 cy; measured/expected = 2.66x = 2400/900MHz.
// Hypothesis: with 8/256 CUs active (3% util, spin-dominated), the power governor
// holds the floor clock (~900MHz); all protocol work was measured in slow-clock time.
// Experiment: the 120 losing blocks become clock-pinning FILLERS (register-only FMA
// burn, no shared-line traffic except a rare agent-scope done-poll on ctl[9]); the 8
// winners bump ctl[9] when finished. Chip util 3% -> ~50% should hold boost clock.
// If k_rec is unchanged, DVFS is refuted and the 6630-cy floor is genuine latency.
__global__ __launch_bounds__(512, 2) void k_rec(
    const float* __restrict__ Wh_f, const float* __restrict__ Wh_b, char* __restrict__ ws)
{
    __shared__ unsigned short hbuf[2 * 16 * 264];   // [parity][16 rows][256 units +8 pad]
    __shared__ char stpad[71680];                   // occupancy limiter -> 1 block/CU
    __shared__ int sRole;
    __shared__ int go;
    int tid = threadIdx.x;

    // ---- XCD team claim (proven r1-r8) ----
    if (tid == 0) {
        ((volatile char*)stpad)[0] = 0;
        go = 0;
        int xcd;
        asm volatile("s_getreg_b32 %0, hwreg(HW_REG_XCC_ID)" : "=s"(xcd));
        xcd &= 7;
        unsigned int* ctl = (unsigned int*)(ws + WS_CTL);
        unsigned int slot = __hip_atomic_fetch_add(&ctl[xcd], 1u,
                              __ATOMIC_RELAXED, __HIP_MEMORY_SCOPE_AGENT);
        int role = -1;
        if (slot < 8u) {
            if (slot == 7u) {
                unsigned int expv = 0u;
                __hip_atomic_compare_exchange_strong(&ctl[8], &expv, (unsigned int)(xcd + 1),
                    __ATOMIC_RELAXED, __ATOMIC_RELAXED, __HIP_MEMORY_SCOPE_AGENT);
            }
            unsigned int ts; long gc = 0;
            do {
                ts = __hip_atomic_fetch_add(&ctl[8], 0u,
                        __ATOMIC_RELAXED, __HIP_MEMORY_SCOPE_AGENT);
            } while (ts == 0u && ++gc < (1L << 26));
            if (ts == (unsigned int)(xcd + 1)) role = (int)slot;
        }
        sRole = role;
    }
    __syncthreads();
    int role = sRole;
    if (role < 0) {
        // ---- FILLER: pin chip clocks until the 8 winners finish (DVFS probe/fix) ----
        unsigned int* ctl = (unsigned int*)(ws + WS_CTL);
        float c0 = 1.0001f + (float)(tid & 7) * 0.001f, c1 = 0.9993f;
        float a = 1.000001f, b = -0.0000013f;
        for (int it = 0; it < (1 << 17); ++it) {        // hard cap ~7ms: fail visibly, no hang
            #pragma unroll
            for (int u = 0; u < 32; ++u) {
                c0 = __builtin_fmaf(a, c0, b);
                c1 = __builtin_fmaf(a, c1, -b);
            }
            asm volatile("" :: "v"(c0), "v"(c1));       // keep chains live (rule #17)
            if ((it & 7) == 0) {
                if (tid == 0) {
                    unsigned int dn = __hip_atomic_load(&ctl[9], __ATOMIC_RELAXED,
                                                        __HIP_MEMORY_SCOPE_AGENT);
                    if (dn >= 8u)
                        __hip_atomic_store(&go, 1, __ATOMIC_RELAXED, __HIP_MEMORY_SCOPE_WORKGROUP);
                }
                if (__hip_atomic_load(&go, __ATOMIC_RELAXED, __HIP_MEMORY_SCOPE_WORKGROUP) != 0)
                    break;
            }
        }
        return;
    }
    int dir = role >> 2, b2 = (role >> 1) & 1, uh = role & 1;

    int w = tid >> 6, l = tid & 63, col = l & 15, quad = l >> 4;
    const float* Wh = dir ? Wh_b : Wh_f;
    const unsigned short* pre = (const unsigned short*)(ws + WS_PRE);
    unsigned short* hall      = (unsigned short*)(ws + WS_HALL);
    unsigned int* flags       = (unsigned int*)(ws + WS_FLG);

    // persistent weight B-fragments, SPLIT BY K-HALF AT LOAD TIME (rule #20):
    // runtime uh appears only in ADDRESSES; array indices are compile-time.
    bf16x8 wfO[4][4], wfP[4][4];
    #pragma unroll
    for (int g = 0; g < 4; ++g) {
        int grow = g * 256 + uh * 128 + w * 16 + col;
        const float* rowp_ = Wh + (size_t)grow * 256 + quad * 8;
        #pragma unroll
        for (int k2 = 0; k2 < 4; ++k2) {
            {
                const float* src = rowp_ + (uh * 4 + k2) * 32;
                float4 x0 = *(const float4*)src;
                float4 x1 = *(const float4*)(src + 4);
                bf16x8 f;
                f[0] = (short)f2bf(x0.x); f[1] = (short)f2bf(x0.y);
                f[2] = (short)f2bf(x0.z); f[3] = (short)f2bf(x0.w);
                f[4] = (short)f2bf(x1.x); f[5] = (short)f2bf(x1.y);
                f[6] = (short)f2bf(x1.z); f[7] = (short)f2bf(x1.w);
                wfO[g][k2] = f;
            }
            {
                const float* src = rowp_ + ((uh ^ 1) * 4 + k2) * 32;
                float4 x0 = *(const float4*)src;
                float4 x1 = *(const float4*)(src + 4);
                bf16x8 f;
                f[0] = (short)f2bf(x0.x); f[1] = (short)f2bf(x0.y);
                f[2] = (short)f2bf(x0.z); f[3] = (short)f2bf(x0.w);
                f[4] = (short)f2bf(x1.x); f[5] = (short)f2bf(x1.y);
                f[6] = (short)f2bf(x1.z); f[7] = (short)f2bf(x1.w);
                wfP[g][k2] = f;
            }
        }
    }
    // zero both hbuf parities (h0 = 0 for own AND partner halves)
    for (int u = tid; u < 4224; u += 512) ((unsigned int*)hbuf)[u] = 0;
    __syncthreads();

    float cst[4] = {0.f, 0.f, 0.f, 0.f};
    int jpre = uh * 2 + (w >> 2);                 // pre j-slice for this wave's units
    int tidp = (b2 * 4 + (w & 3)) * 64 + l;       // pre lane index
    size_t rb = (size_t)(dir * 2 + b2) * 513;     // hall region row (x4096 ushorts)
    int rrow = l >> 2, cpart = l & 3;
    int ownKB = uh * 128;                         // LDS col base of own K half (ushorts)
    int prtKB = (uh ^ 1) * 128;

    // preload pre for st=0
    uint4 pn0, pn1;
    {
        int s0 = dir ? 511 : 0;
        const uint4* pp = (const uint4*)(pre + ((((size_t)(dir * 512 + s0)) * 4 + jpre) * 512 + tidp) * 16);
        pn0 = pp[0]; pn1 = pp[1];
    }

    for (int st = 0; st < 512; ++st) {
        int cur = st & 1;
        unsigned short* hb_cur = hbuf + cur * 4224;
        unsigned short* hb_nxt = hbuf + (cur ^ 1) * 4224;
        uint4 p0 = pn0, p1 = pn1;                // pre(st), prefetched last step
        // prefetch pre(st+1): used a full step later, never drained on critical path
        {
            int stn = (st < 511) ? st + 1 : st;
            int sn = dir ? (511 - stn) : stn;
            const uint4* pp = (const uint4*)(pre + ((((size_t)(dir * 512 + sn)) * 4 + jpre) * 512 + tidp) * 16);
            pn0 = pp[0]; pn1 = pp[1];
        }

        f32x4 acc[4];
        #pragma unroll
        for (int g = 0; g < 4; ++g) acc[g] = (f32x4){0.f, 0.f, 0.f, 0.f};

        // ---- phase A: own-half K MFMAs (own h already in hb_cur; wfO compile-time idx) ----
        #pragma unroll
        for (int k2 = 0; k2 < 4; ++k2) {
            bf16x8 af = *(const bf16x8*)(hb_cur + col * 264 + ownKB + k2 * 32 + quad * 8);
            #pragma unroll
            for (int g = 0; g < 4; ++g)
                acc[g] = __builtin_amdgcn_mfma_f32_16x16x32_bf16(af, wfO[g][k2], acc[g], 0, 0, 0);
        }

        // ---- phase B: detect partner flag(st), load partner 4KB half ----
        if (st > 0) {
            if (tid == 0) {
                unsigned int* fl = flags + ((rb + st) * 2 + (uh ^ 1)) * 32;
                int rnd = 0;
                for (;;) {
                    unsigned int expv = 0u;
                    __hip_atomic_compare_exchange_strong(fl, &expv, 0u,
                        __ATOMIC_RELAXED, __ATOMIC_RELAXED, __HIP_MEMORY_SCOPE_WORKGROUP);
                    if (expv != 0u) break;
                    if (++rnd > (1 << 16)) break;       // guard: fail visibly, no hang
                }
                __hip_atomic_store(&go, st, __ATOMIC_RELAXED, __HIP_MEMORY_SCOPE_WORKGROUP);
            }
            long sg = 0;
            while (__hip_atomic_load(&go, __ATOMIC_RELAXED, __HIP_MEMORY_SCOPE_WORKGROUP) < st) {
                if (++sg > (1L << 20)) break;           // guard: fail visibly, no hang
            }
            asm volatile("" ::: "memory");
            // one-shot plain 8B loads (cold lines, RMW-detected): 512 chunks
            size_t srcb = (rb + st) * 4096 + (size_t)(uh ^ 1) * 2048 + (size_t)tid * 4;
            unsigned long long pv = *(const unsigned long long*)(hall + srcb);
            int prow = tid >> 5, ploc = (tid * 4) & 127;
            *(unsigned long long*)(hb_cur + prow * 264 + prtKB + ploc) = pv;
        }
        lds_barrier();                                  // partner half visible to all waves

        // ---- phase C: partner-half K MFMAs (wfP compile-time idx) ----
        #pragma unroll
        for (int k2 = 0; k2 < 4; ++k2) {
            bf16x8 af = *(const bf16x8*)(hb_cur + col * 264 + prtKB + k2 * 32 + quad * 8);
            #pragma unroll
            for (int g = 0; g < 4; ++g)
                acc[g] = __builtin_amdgcn_mfma_f32_16x16x32_bf16(af, wfP[g][k2], acc[g], 0, 0, 0);
        }

        // ---- phase D: z, gates, h(st+1); publish own half; flag ----
        unsigned int pw[8] = {p0.x, p0.y, p0.z, p0.w, p1.x, p1.y, p1.z, p1.w};
        float z[4][4];
        #pragma unroll
        for (int g = 0; g < 4; ++g) {
            #pragma unroll
            for (int r2 = 0; r2 < 2; ++r2) {
                unsigned int u = pw[g * 2 + r2];
                z[g][r2 * 2]     = acc[g][r2 * 2]     + bf2f((unsigned short)(u & 0xffff));
                z[g][r2 * 2 + 1] = acc[g][r2 * 2 + 1] + bf2f((unsigned short)(u >> 16));
            }
        }
        unsigned short hb16[4];
        #pragma unroll
        for (int r = 0; r < 4; ++r) {   // gates i,f,g,o; lane = (batch row quad*4+r, unit uh*128+w*16+col)
            float ci = sigf(z[1][r]) * cst[r] + sigf(z[0][r]) * tanhf_(z[2][r]);
            cst[r] = ci;
            hb16[r] = f2bf(sigf(z[3][r]) * tanhf_(ci));
        }
        // stage own h(st+1) tile into next-parity hbuf (2B LDS writes, wave-local region)
        #pragma unroll
        for (int r = 0; r < 4; ++r)
            hb_nxt[(quad * 4 + r) * 264 + ownKB + w * 16 + col] = hb16[r];
        asm volatile("s_waitcnt lgkmcnt(0)" ::: "memory");    // wave's own writes done
        __builtin_amdgcn_sched_barrier(0);
        // readback 8B chunks (same-wave data) and publish to global half-region
        unsigned long long hv = *(const unsigned long long*)
            (hb_nxt + rrow * 264 + ownKB + w * 16 + cpart * 4);
        size_t pub = (rb + st + 1) * 4096 + (size_t)uh * 2048 + rrow * 128 + w * 16 + cpart * 4;
        *(unsigned long long*)(hall + pub) = hv;
        // drain publish + full barrier (also orders hb_nxt writes for next iter), then flag
        asm volatile("s_waitcnt vmcnt(0) lgkmcnt(0)" ::: "memory");
        __builtin_amdgcn_s_barrier();
        __builtin_amdgcn_sched_barrier(0);
        if (tid == 0)
            (void)__hip_atomic_exchange(flags + ((rb + st + 1) * 2 + uh) * 32, 1u,
                                        __ATOMIC_RELAXED, __HIP_MEMORY_SCOPE_WORKGROUP);
    }

    // winner done: release the fillers
    if (tid == 0)
        __hip_atomic_fetch_add((unsigned int*)(ws + WS_CTL) + 9, 1u,
                               __ATOMIC_RELAXED, __HIP_MEMORY_SCOPE_AGENT);
}

// ============ kernel 4: emissions e[b][s][t] = [hf|hb] . Wt[t] + bt ============
__global__ __launch_bounds__(256) void k_emis(
    const float* __restrict__ Wt, const float* __restrict__ bt, char* __restrict__ ws)
{
    __shared__ float WtL[16 * 528];
    __shared__ unsigned short hrow[16 * 536];
    __shared__ float btL[16];
    int blk = blockIdx.x, tid = threadIdx.x;
    int sbb = blk * 16;
    int s = sbb >> 5, bbase = sbb & 31;     // 16 batch rows per block, fixed s
    int b2 = bbase >> 4;
    const unsigned short* hall = (const unsigned short*)(ws + WS_HALL);
    float* emis = (float*)(ws + WS_EMIS);
    #pragma unroll
    for (int i = 0; i < 8; ++i) {           // Wt 16x512 f32 -> LDS
        int c = tid + i * 256;
        int trow = c >> 7, c128 = c & 127;
        float4 v = *(const float4*)(Wt + (size_t)trow * 512 + c128 * 4);
        *(float4*)(WtL + trow * 528 + c128 * 4) = v;
    }
    #pragma unroll
    for (int i = 0; i < 4; ++i) {           // h rows: [i][0..255]=hf(s), [i][256..511]=hb(s)
        int c = tid + i * 256;
        int row = c >> 6, c6 = c & 63, dsel = c6 >> 5, c16 = c6 & 31;
        int uh = (c16 >> 4) & 1, within = (c16 & 15) * 8;
        size_t base = (dsel == 0)
            ? ((size_t)(b2 * 513) + (size_t)(s + 1)) * 4096
            : ((size_t)((2 + b2) * 513) + (size_t)(512 - s)) * 4096;
        uint4 v = *(const uint4*)(hall + base + (size_t)uh * 2048 + row * 128 + within);
        *(uint4*)(hrow + row * 536 + dsel * 256 + c16 * 8) = v;
    }
    if (tid < 16) btL[tid] = bt[tid];
    __syncthreads();
    int t = tid >> 4, i = tid & 15;
    float acc = btL[t];
    const float* wrow = WtL + t * 528;
    const unsigned short* hr = hrow + i * 536;
    #pragma unroll 8
    for (int k = 0; k < 512; k += 4) {
        uint2 hu = *(const uint2*)(hr + k);
        float4 wv = *(const float4*)(wrow + k);
        acc += bf2f((unsigned short)(hu.x & 0xffff)) * wv.x
             + bf2f((unsigned short)(hu.x >> 16))    * wv.y
             + bf2f((unsigned short)(hu.y & 0xffff)) * wv.z
             + bf2f((unsigned short)(hu.y >> 16))    * wv.w;
    }
    emis[((size_t)(bbase + i) * 512 + s) * 16 + t] = acc;
}

// ============ kernel 5: CRF chunk products (log-semiring, associative) ============
__global__ __launch_bounds__(256) void k_crfc(const float* __restrict__ trans, char* __restrict__ ws)
{
    __shared__ float trL[16 * 17];
    __shared__ float est[16 * 16];
    __shared__ float Pb[2][16 * 17];
    int blk = blockIdx.x, tid = threadIdx.x;
    int b = blk >> 5, c = blk & 31;
    int t = tid >> 4, p = tid & 15;
    const float* emis = (const float*)(ws + WS_EMIS);
    float* chk = (float*)(ws + WS_CHK);
    trL[t * 17 + p] = trans[t * 16 + p];
    est[t * 16 + p] = emis[((size_t)b * 512 + c * 16 + t) * 16 + p];
    __syncthreads();
    float tr[16];
    #pragma unroll
    for (int q = 0; q < 16; ++q) tr[q] = trL[t * 17 + q];
    float out = trL[t * 17 + p] + est[0 * 16 + t];
    Pb[0][t * 17 + p] = out;
    __syncthreads();
    int cur = 0;
    for (int si = 1; si < 16; ++si) {
        float v[16]; float mx = -3.0e38f;
        #pragma unroll
        for (int q = 0; q < 16; ++q) { v[q] = tr[q] + Pb[cur][q * 17 + p]; mx = fmaxf(mx, v[q]); }
        float ss = 0.f;
        #pragma unroll
        for (int q = 0; q < 16; ++q) ss += __expf(v[q] - mx);
        out = est[si * 16 + t] + mx + __logf(ss);
        Pb[1 - cur][t * 17 + p] = out;
        __syncthreads();
        cur = 1 - cur;
    }
    chk[(size_t)(b * 32 + c) * 256 + t * 16 + p] = out;
}

// ============ kernel 6: fold 32 chunk matrices per batch, apply alpha0/stop, emit log_Z ============
__global__ __launch_bounds__(256) void k_crff(
    const float* __restrict__ trans, char* __restrict__ ws, float* __restrict__ out)
{
    __shared__ float Cst[16 * 17];
    __shared__ float Pb[2][16 * 17];
    __shared__ float af[16];
    int b = blockIdx.x, tid = threadIdx.x;
    int t = tid >> 4, p = tid & 15;
    const float* chk = (const float*)(ws + WS_CHK);
    Pb[0][t * 17 + p] = chk[(size_t)(b * 32) * 256 + t * 16 + p];
    __syncthreads();
    int cur = 0;
    for (int ci = 1; ci < 32; ++ci) {
        Cst[t * 17 + p] = chk[(size_t)(b * 32 + ci) * 256 + t * 16 + p];
        __syncthreads();
        float v[16]; float mx = -3.0e38f;
        #pragma unroll
        for (int q = 0; q < 16; ++q) { v[q] = Cst[t * 17 + q] + Pb[cur][q * 17 + p]; mx = fmaxf(mx, v[q]); }
        float ss = 0.f;
        #pragma unroll
        for (int q = 0; q < 16; ++q) ss += __expf(v[q] - mx);
        float outv = mx + __logf(ss);
        Pb[1 - cur][t * 17 + p] = outv;
        __syncthreads();
        cur = 1 - cur;
    }
    float vfin = Pb[cur][t * 17 + p] + ((p == 14) ? 0.0f : -10000.0f);  // alpha0: START=14
    Cst[t * 17 + p] = vfin;
    __syncthreads();
    if (tid < 16) {
        float mx = -3.0e38f;
        for (int q = 0; q < 16; ++q) mx = fmaxf(mx, Cst[tid * 17 + q]);
        float ss = 0.f;
        for (int q = 0; q < 16; ++q) ss += __expf(Cst[tid * 17 + q] - mx);
        af[tid] = mx + __logf(ss) + trans[15 * 16 + tid];               // STOP=15
    }
    __syncthreads();
    if (tid == 0) {
        float mx = -3.0e38f;
        for (int q = 0; q < 16; ++q) mx = fmaxf(mx, af[q]);
        float ss = 0.f;
        for (int q = 0; q < 16; ++q) ss += __expf(af[q] - mx);
        out[b] = mx + __logf(ss);
    }
}

extern "C" void kernel_launch(void* const* d_in, const int* in_sizes, int n_in,
                              void* d_out, int out_size, void* d_ws, size_t ws_size,
                              hipStream_t stream)
{
    const int*   tokens = (const int*)d_in[0];
    const float* embed  = (const float*)d_in[1];
    const float* Wi_f   = (const float*)d_in[2];
    const float* Wh_f   = (const float*)d_in[3];
    const float* bi_f   = (const float*)d_in[4];
    const float* bh_f   = (const float*)d_in[5];
    const float* Wi_b   = (const float*)d_in[6];
    const float* Wh_b   = (const float*)d_in[7];
    const float* bi_b   = (const float*)d_in[8];
    const float* bh_b   = (const float*)d_in[9];
    const float* Wt     = (const float*)d_in[10];
    const float* bt     = (const float*)d_in[11];
    const float* trans  = (const float*)d_in[12];
    char* ws = (char*)d_ws;
    float* out = (float*)d_out;

    hipLaunchKernelGGL(k_prep, dim3(2560), dim3(256), 0, stream,
                       tokens, embed, Wi_f, Wi_b, bi_f, bh_f, bi_b, bh_b, ws);
    hipLaunchKernelGGL(k_pregemm, dim3(4096), dim3(256), 0, stream, ws);
    hipLaunchKernelGGL(k_rec, dim3(128), dim3(512), 0, stream, Wh_f, Wh_b, ws);
    hipLaunchKernelGGL(k_emis, dim3(1024), dim3(256), 0, stream, Wt, bt, ws);
    hipLaunchKernelGGL(k_crfc, dim3(1024), dim3(256), 0, stream, trans, ws);
    hipLaunchKernelGGL(k_crff, dim3(32), dim3(256), 0, stream, trans, ws, out);
}